// Round 7
// baseline (192.224 us; speedup 1.0000x reference)
//
#include <hip/hip_runtime.h>

#define BD 8
#define CD 128
#define HD 96
#define WD 96
#define PD 9216      // H*W
#define ND 73728     // B*P

typedef __attribute__((ext_vector_type(8))) short short8;
typedef __attribute__((ext_vector_type(4))) float f32x4;

__device__ inline float bfu2f(unsigned int u) { return __uint_as_float(u << 16); }
__device__ inline unsigned short f2bfu(float f) {
  unsigned int u = __float_as_uint(f);
  u += 0x7fffu + ((u >> 16) & 1u);   // RNE
  return (unsigned short)(u >> 16);
}

template<bool F32>
__device__ __forceinline__ float ldv(const void* __restrict__ p, size_t i) {
  if constexpr (F32) return ((const float*)p)[i];
  else return bfu2f(((const unsigned short*)p)[i]);
}

// ---------------- init: dmm min/max slots + detect counters ----------------
__global__ void k_init(unsigned long long* dmm, int* cnt) {
  int t = threadIdx.x;
  if (t < 8) dmm[t] = 0x7FEFFFFFFFFFFFFFULL;  // min slots (DBL_MAX bits)
  else if (t < 16) dmm[t] = 0ULL;             // max slots
  if (t == 16) { cnt[0] = 0; cnt[1] = 0; }
}

// ---------------- storage-dtype detector ----------------
__global__ void k_detect(const unsigned int* __restrict__ xw, int* __restrict__ cnt) {
  int t = blockIdx.x * 256 + threadIdx.x;     // 64 blocks -> 16384 uint4 = 65536 words
  uint4 w = ((const uint4*)xw)[t];
  int lz = (int)((w.x & 0xFFFFu) == 0u) + (int)((w.y & 0xFFFFu) == 0u) +
           (int)((w.z & 0xFFFFu) == 0u) + (int)((w.w & 0xFFFFu) == 0u);
  int e2 = (int)(((w.x >> 7) & 0xFFu) == 0xFFu) + (int)(((w.y >> 7) & 0xFFu) == 0xFFu) +
           (int)(((w.z >> 7) & 0xFFu) == 0xFFu) + (int)(((w.w >> 7) & 0xFFu) == 0xFFu);
  #pragma unroll
  for (int off = 32; off; off >>= 1) {
    lz += __shfl_down(lz, off);
    e2 += __shfl_down(e2, off);
  }
  if ((threadIdx.x & 63) == 0) { atomicAdd(&cnt[0], lz); atomicAdd(&cnt[1], e2); }
}

__global__ void k_flag(const int* __restrict__ cnt, int* __restrict__ flag) {
  *flag = (cnt[0] > 4096 || cnt[1] > 0) ? 1 : 0;  // 1 = float32 storage
}

// ---------------- canonical bf16 weights for MFMA B-operands ----------------
__global__ void k_cvtw(const void* __restrict__ w1, const void* __restrict__ w2,
                       unsigned short* __restrict__ wc, const int* __restrict__ flag) {
  bool f32 = (*flag != 0);
  int t = blockIdx.x * 256 + threadIdx.x;   // 0..65535
  if (t < 32768)
    wc[t] = f32 ? f2bfu(((const float*)w1)[t]) : ((const unsigned short*)w1)[t];
  else {
    int u = t - 32768;
    wc[t] = f32 ? f2bfu(((const float*)w2)[u]) : ((const unsigned short*)w2)[u];
  }
}

// ---------------- canonical f32 small params: gw(128) gb(128) b1(256) b2(128) ----------------
__global__ void k_cvtb(const void* __restrict__ gw, const void* __restrict__ gb,
                       const void* __restrict__ b1, const void* __restrict__ b2,
                       float* __restrict__ prm, const int* __restrict__ flag) {
  bool f32 = (*flag != 0);
  int t = threadIdx.x;
  for (int i = t; i < 640; i += 256) {
    float v;
    if (i < 128)      v = f32 ? ((const float*)gw)[i]       : bfu2f(((const unsigned short*)gw)[i]);
    else if (i < 256) v = f32 ? ((const float*)gb)[i - 128] : bfu2f(((const unsigned short*)gb)[i - 128]);
    else if (i < 512) v = f32 ? ((const float*)b1)[i - 256] : bfu2f(((const unsigned short*)b1)[i - 256]);
    else              v = f32 ? ((const float*)b2)[i - 512] : bfu2f(((const unsigned short*)b2)[i - 512]);
    prm[i] = v;
  }
}

// ---------------- transpose -> pixel-major f32 xpm + channel stats + GN partials ----------------
// XCD-swizzled (same image->XCD pinning as k_ipg) so xpm/avg/nrm land in the
// reader's L2. nrm2 = quarter-associated sum(v^2): EXACTLY the chain k_ipg's
// center dot would produce (per-quarter i-ascending, ((q0+q1)+q2)+q3) -> k_ipg
// can skip the k=4 dot bit-identically. nrm keeps the original sequential chain.
template<bool F32>
__device__ __forceinline__ void pmt_body(const void* __restrict__ x,
                                         float* __restrict__ xpm,
                                         double* __restrict__ avg, double* __restrict__ nrm,
                                         double* __restrict__ nrm2,
                                         double* __restrict__ gpart,
                                         float (*tile)[132], int lb) {
  const int t = threadIdx.x, px = t & 63, ci = t >> 6;
  const int gp0 = lb * 64, b = gp0 / PD, p0 = gp0 - b * PD;
  double sg[4] = {0.0, 0.0, 0.0, 0.0}, qg[4] = {0.0, 0.0, 0.0, 0.0};
  for (int j = 0; j < 32; ++j) {
    int c = ci * 32 + j;
    float v = ldv<F32>(x, (size_t)(b * CD + c) * PD + p0 + px);   // coalesced
    tile[px][c] = v;
    sg[j >> 3] += (double)v;
    qg[j >> 3] += (double)v * (double)v;
  }
  #pragma unroll
  for (int g = 0; g < 4; ++g) {
    #pragma unroll
    for (int off = 32; off; off >>= 1) {
      sg[g] += __shfl_down(sg[g], off);
      qg[g] += __shfl_down(qg[g], off);
    }
  }
  if (px == 0) {
    double* gp_ = gpart + (size_t)lb * 32;
    #pragma unroll
    for (int g = 0; g < 4; ++g) {
      gp_[(ci * 4 + g) * 2 + 0] = sg[g];
      gp_[(ci * 4 + g) * 2 + 1] = qg[g];
    }
  }
  __syncthreads();
  for (int i = t; i < 2048; i += 256) {
    int r = i >> 5, seg = i & 31;
    *(float4*)(xpm + (size_t)(gp0 + r) * 128 + seg * 4) = *(const float4*)&tile[r][seg * 4];
  }
  if (t < 64) {
    double s = 0.0, q = 0.0;
    for (int c = 0; c < 128; ++c) {
      float v = tile[t][c];
      s += (double)v;
      q += (double)v * (double)v;
    }
    double qq[4] = {0.0, 0.0, 0.0, 0.0};
    #pragma unroll
    for (int g = 0; g < 4; ++g)
      for (int i = 0; i < 32; ++i) {
        float v = tile[t][g * 32 + i];
        qq[g] += (double)v * (double)v;
      }
    avg[gp0 + t] = s * (1.0 / 128.0);
    nrm[gp0 + t] = sqrt(q);
    nrm2[gp0 + t] = ((qq[0] + qq[1]) + qq[2]) + qq[3];
  }
}
__global__ __launch_bounds__(256) void k_pmt(const void* __restrict__ x,
                                             const int* __restrict__ flag,
                                             float* __restrict__ xpm,
                                             double* __restrict__ avg,
                                             double* __restrict__ nrm,
                                             double* __restrict__ nrm2,
                                             double* __restrict__ gpart) {
  __shared__ float tile[64][132];
  const int lb = (blockIdx.x & 7) * 144 + (blockIdx.x >> 3);  // XCD swizzle (1152 = 8*144)
  if (*flag) pmt_body<true>(x, xpm, avg, nrm, nrm2, gpart, tile, lb);
  else pmt_body<false>(x, xpm, avg, nrm, nrm2, gpart, tile, lb);
}

// ---------------- GN finalize: fold 144 block-partials per (b,g) ----------------
__global__ void k_gn2(const double* __restrict__ gpart, float* __restrict__ gn) {
  const int bg = blockIdx.x;                 // b*16 + g
  const int b = bg >> 4, g = bg & 15;
  const int t = threadIdx.x;                 // 64 threads
  double s = 0.0, q = 0.0;
  for (int i = t; i < 144; i += 64) {
    const double* pp = gpart + (size_t)(b * 144 + i) * 32 + g * 2;
    s += pp[0];
    q += pp[1];
  }
  #pragma unroll
  for (int off = 32; off; off >>= 1) {
    s += __shfl_down(s, off);
    q += __shfl_down(q, off);
  }
  if (t == 0) {
    double mu = s / 73728.0;
    double var = q / 73728.0 - mu * mu;
    gn[bg] = (float)mu;
    gn[128 + bg] = (float)(1.0 / sqrt(var + 1e-5));
  }
}

// zero-padded Laplacian on the mean map
__device__ inline double lap_df(const double* __restrict__ a, int b, int y, int x) {
  const double* ab = a + (size_t)b * PD;
  double v = 4.0 * ab[y * WD + x];
  if (y > 0)      v -= ab[(y - 1) * WD + x];
  if (y < HD - 1) v -= ab[(y + 1) * WD + x];
  if (x > 0)      v -= ab[y * WD + x - 1];
  if (x < WD - 1) v -= ab[y * WD + x + 1];
  return fabs(v);
}

// ---------------- per-batch min/max of df (XCD-swizzled: 288 = 8*36) ----------------
__global__ void k_minmax(const double* __restrict__ avg, unsigned long long* __restrict__ dmm) {
  __shared__ double mnW[4], mxW[4];
  int t = threadIdx.x;
  const int lb = (blockIdx.x & 7) * 36 + (blockIdx.x >> 3);
  int gp = lb * 256 + t;                    // 256 | PD -> block never crosses batch
  int b = gp / PD, p = gp - b * PD;
  double mn = lap_df(avg, b, p / WD, p % WD);
  double mx = mn;
  #pragma unroll
  for (int off = 32; off; off >>= 1) {
    mn = fmin(mn, __shfl_down(mn, off));
    mx = fmax(mx, __shfl_down(mx, off));
  }
  if ((t & 63) == 0) { mnW[t >> 6] = mn; mxW[t >> 6] = mx; }
  __syncthreads();
  if (t == 0) {
    mn = fmin(fmin(mnW[0], mnW[1]), fmin(mnW[2], mnW[3]));
    mx = fmax(fmax(mxW[0], mxW[1]), fmax(mxW[2], mxW[3]));
    atomicMin(&dmm[b], (unsigned long long)__double_as_longlong(mn));
    atomicMax(&dmm[b + 8], (unsigned long long)__double_as_longlong(mx));
  }
}

// reflect neighbor table (global indices; used for nrm lookups in phase 1b)
__device__ __forceinline__ void neigh9(int y, int xx, int* q) {
  #pragma unroll
  for (int dy = 0; dy < 3; ++dy) {
    int yy = y + dy - 1;
    yy = yy < 0 ? -yy : (yy >= HD ? 2 * HD - 2 - yy : yy);
    #pragma unroll
    for (int dx = 0; dx < 3; ++dx) {
      int xr = xx + dx - 1;
      xr = xr < 0 ? -xr : (xr >= WD ? 2 * WD - 2 - xr : xr);
      q[dy * 3 + dx] = yy * WD + xr;
    }
  }
}

// ---------------- k_ipg: IPG + GN -> eg, 8x8 tiles + LDS halo, SYMMETRIC DOTS ----------------
// dot(x_p,x_q) is bit-symmetric (products commute, same i-order, same quarter
// association) -> each pixel computes only k=0..3; k=5..8 come from the
// neighbor's mirror via sdl[64][4] unless the neighbor is outside the tile
// (edge fallback, predicate uniform per pixel-quad). k=4 (center) == nrm2
// (quarter-associated sum v^2 from k_pmt, chain-identical). Dots/pixel 9 -> 4.7.
__global__ __launch_bounds__(256, 3) void k_ipg(const float* __restrict__ xpm,
                                                const double* __restrict__ avg,
                                                const double* __restrict__ nrm,
                                                const double* __restrict__ nrm2,
                                                const unsigned long long* __restrict__ dmm,
                                                const float* __restrict__ gn,
                                                const float* __restrict__ prm,
                                                unsigned short* __restrict__ eg) {
  __shared__ float tileF[12800];            // 51200 B halo: 10x10 px x 128 ch f32
  __shared__ double sdl[64][4];             // 2048 B: canonical dots k=0..3 per pixel
  float4* tile4 = (float4*)tileF;
  const float* gwf = prm;
  const float* gbf = prm + 128;

  const int t = threadIdx.x;
  const int lb = (blockIdx.x & 7) * 144 + (blockIdx.x >> 3);  // XCD swizzle (1152 = 8*144)
  const int b = lb / 144;
  const int tid = lb - b * 144;
  const int ty = tid / 12, tx = tid - ty * 12;                // 12x12 tiles of 8x8
  const int y0 = ty * 8, x0 = tx * 8;

  // ---- stage halo: 100 pixel-rows of 512 B, coalesced; XOR-swizzled LDS ----
  {
    const int s = t & 31, hpb = t >> 5;
    #pragma unroll
    for (int it = 0; it < 13; ++it) {
      int hp = it * 8 + hpb;
      if (hp < 100) {
        int hr = hp / 10, hc = hp - hr * 10;
        int gy = y0 - 1 + hr; gy = gy < 0 ? -gy : (gy >= HD ? 2 * HD - 2 - gy : gy);
        int gx = x0 - 1 + hc; gx = gx < 0 ? -gx : (gx >= WD ? 2 * WD - 2 - gx : gx);
        const float4* src = (const float4*)(xpm + (size_t)(b * PD + gy * WD + gx) * 128) + s;
        tile4[(hp * 32 + s) ^ (hp & 7)] = *src;
      }
    }
  }
  __syncthreads();

  const int a = t >> 2, q = t & 3;            // pixel-in-tile, channel quarter
  const int yl = a >> 3, xl = a & 7;
  const int y = y0 + yl, xx = x0 + xl;
  const int p = y * WD + xx;
  const int cpix = (yl + 1) * 10 + (xl + 1);
  const int cub = cpix * 32 + q * 8, csw = cpix & 7;

  // edge-fallback predicates (uniform across the 4 quarter lanes of a pixel)
  const bool nb5 = (xl == 7);
  const bool nb6 = (yl == 7) || (xl == 0);
  const bool nb7 = (yl == 7);
  const bool nb8 = (yl == 7) || (xl == 7);

  // ---- phase 1a: f64 dots (canonical + edge fallbacks), cross-quarter reduced ----
  double d[9];
  {
    float cv[32];
    #pragma unroll
    for (int j4 = 0; j4 < 8; ++j4)
      *(float4*)(cv + 4 * j4) = tile4[(cub + j4) ^ csw];
    #pragma unroll
    for (int k = 0; k < 9; ++k) {
      if (k == 4) continue;                         // center == nrm2 (chain-identical)
      bool need = (k < 4) || (k == 5 ? nb5 : k == 6 ? nb6 : k == 7 ? nb7 : nb8);
      if (need) {
        int dy = k / 3, dx = k - dy * 3;
        int pix = (yl + dy) * 10 + (xl + dx);
        int ub = pix * 32 + q * 8, sw = pix & 7;
        double acc = 0.0;
        #pragma unroll
        for (int seg = 0; seg < 8; ++seg) {
          float4 nv = tile4[(ub + seg) ^ sw];
          acc += (double)cv[seg * 4 + 0] * (double)nv.x;
          acc += (double)cv[seg * 4 + 1] * (double)nv.y;
          acc += (double)cv[seg * 4 + 2] * (double)nv.z;
          acc += (double)cv[seg * 4 + 3] * (double)nv.w;
        }
        // cross-quarter sum in-wave, SAME association as original: ((q0+q1)+q2)+q3
        double v1 = __shfl_down(acc, 1);
        double v2 = __shfl_down(acc, 2);
        double v3 = __shfl_down(acc, 3);
        d[k] = ((acc + v1) + v2) + v3;
      }
    }
  }
  if (q == 0) {
    sdl[a][0] = d[0]; sdl[a][1] = d[1]; sdl[a][2] = d[2]; sdl[a][3] = d[3];
  }
  __syncthreads();

  // ---- phase 1b: count, ranks, softmax weights (q==0 lanes; 16/wave) ----
  float wv[9];
  #pragma unroll
  for (int j = 0; j < 9; ++j) wv[j] = 0.f;
  if (q == 0) {
    int qg[9];
    neigh9(y, xx, qg);
    double dmin = __longlong_as_double((long long)dmm[b]);
    double dmax = __longlong_as_double((long long)dmm[b + 8]);
    double df = lap_df(avg, b, y, xx);
    double dn = (df - dmin) / (dmax - dmin + 1e-8);
    int kk = 1 + (int)rint(dn * 7.0);
    kk = kk < 1 ? 1 : (kk > 8 ? 8 : kk);

    double sd[9];
    sd[0] = d[0]; sd[1] = d[1]; sd[2] = d[2]; sd[3] = d[3];
    sd[4] = nrm2[b * PD + p];
    sd[5] = nb5 ? d[5] : sdl[a + 1][3];      // (yl,   xl+1) mirror: left
    sd[6] = nb6 ? d[6] : sdl[a + 7][2];      // (yl+1, xl-1) mirror: upper-right
    sd[7] = nb7 ? d[7] : sdl[a + 8][1];      // (yl+1, xl  ) mirror: up
    sd[8] = nb8 ? d[8] : sdl[a + 9][0];      // (yl+1, xl+1) mirror: upper-left

    double np_ = fmax(nrm[b * PD + p], 1e-12);
    #pragma unroll
    for (int k = 0; k < 9; ++k) {
      double nq = fmax(nrm[b * PD + qg[k]], 1e-12);
      sd[k] = sd[k] / (np_ * nq);           // normalized sim
    }
    float w[9];
    float wsum = 0.f;
    #pragma unroll
    for (int j = 0; j < 9; ++j) {
      int rank = 0;
      #pragma unroll
      for (int i = 0; i < 9; ++i)
        rank += (sd[i] > sd[j]) || (sd[i] == sd[j] && i < j);   // stable tie rule
      w[j] = (rank < kk) ? expf((float)sd[j]) : 0.f;
      wsum += w[j];
    }
    float inv = 1.f / wsum;
    #pragma unroll
    for (int j = 0; j < 9; ++j) wv[j] = w[j] * inv;
  }
  #pragma unroll
  for (int j = 0; j < 9; ++j) wv[j] = __shfl(wv[j], (t & 63) & ~3);  // broadcast to quarters

  // ---- phase 1c: aggregate (LDS) + GroupNorm -> eg (bf16, pixel-major) ----
  {
    float og[32];
    #pragma unroll
    for (int j = 0; j < 32; ++j) og[j] = 0.f;
    #pragma unroll
    for (int k = 0; k < 9; ++k) {
      int dy = k / 3, dx = k - dy * 3;
      int pix = (yl + dy) * 10 + (xl + dx);
      int ub = pix * 32 + q * 8, sw = pix & 7;
      #pragma unroll
      for (int seg = 0; seg < 8; ++seg) {
        float4 nv = tile4[(ub + seg) ^ sw];
        og[seg * 4 + 0] += wv[k] * nv.x;
        og[seg * 4 + 1] += wv[k] * nv.y;
        og[seg * 4 + 2] += wv[k] * nv.z;
        og[seg * 4 + 3] += wv[k] * nv.w;
      }
    }
    const int g16 = b * 16;
    unsigned short* egr = eg + (size_t)(b * PD + p) * 128 + q * 32;
    #pragma unroll
    for (int seg = 0; seg < 4; ++seg) {
      float4 cA = tile4[(cub + seg * 2) ^ csw];       // center re-read (bit-identical)
      float4 cB = tile4[(cub + seg * 2 + 1) ^ csw];
      float cvv[8] = {cA.x, cA.y, cA.z, cA.w, cB.x, cB.y, cB.z, cB.w};
      int g = q * 4 + seg;
      float mu = gn[g16 + g], rs = gn[128 + g16 + g];
      unsigned int pkd[4];
      #pragma unroll
      for (int j = 0; j < 8; ++j) {
        int c = q * 32 + seg * 8 + j;
        float e = og[seg * 8 + j] + (cvv[j] - mu) * rs * gwf[c] + gbf[c];
        unsigned int h = (unsigned int)f2bfu(e);
        if (j & 1) pkd[j >> 1] |= h << 16;
        else pkd[j >> 1] = h;
      }
      uint4 v; v.x = pkd[0]; v.y = pkd[1]; v.z = pkd[2]; v.w = pkd[3];
      *(uint4*)(egr + seg * 8) = v;                   // 16B store; wave covers 4KB contiguous
    }
  }
}

// ---------------- k_ffn: eg -> FFN -> out, wave-per-N-quarter (weights in regs) ----------------
__global__ __launch_bounds__(256, 3) void k_ffn(const unsigned short* __restrict__ eg,
                                                const float* __restrict__ prm,
                                                const unsigned short* __restrict__ wc,
                                                float* __restrict__ outp) {
  __shared__ unsigned short et[64][136];    // 17408 B
  __shared__ unsigned short Hl[64][264];    // 33792 B
  const float* b1f = prm + 256;
  const float* b2f = prm + 512;

  const int t = threadIdx.x;
  const int lb = (blockIdx.x & 7) * 144 + (blockIdx.x >> 3);  // XCD swizzle: match k_ipg's image->XCD map
  const int gp0 = lb * 64;                  // 64 | PD -> block within one batch
  const int b = gp0 / PD, p0b = gp0 - b * PD;

  const unsigned short* wc1 = wc;          // w1 [256][128]
  const unsigned short* wc2 = wc + 32768;  // w2 [128][256]
  const int lane = t & 63, wave = t >> 6;
  const int r16 = lane & 15, quad = lane >> 4;

  // ---- stage eg rows -> et LDS (16 KB contiguous, fully coalesced) ----
  {
    const uint4* eg4 = (const uint4*)(eg + (size_t)gp0 * 128);
    #pragma unroll
    for (int it = 0; it < 4; ++it) {
      int lin = it * 256 + t;               // 1024 uint4 = 64 rows x 16
      int row = lin >> 4, c8 = lin & 15;
      *(uint4*)&et[row][c8 * 8] = eg4[lin];
    }
  }
  // ---- preload wave's w1 quarter (n in [wave*64, wave*64+64)) into regs ----
  short8 wb1[16];
  #pragma unroll
  for (int kk = 0; kk < 4; ++kk)
    #pragma unroll
    for (int nt = 0; nt < 4; ++nt)
      wb1[kk * 4 + nt] = *(const short8*)(wc1 + (size_t)(wave * 64 + nt * 16 + r16) * 128 + kk * 32 + quad * 8);
  __syncthreads();

  // ---- stage 1: H[64 px][wave's 64 n] = relu(et * W1^T + b1), pure-reg MFMA ----
  f32x4 acc[16];
  #pragma unroll
  for (int i = 0; i < 16; ++i) acc[i] = (f32x4){0.f, 0.f, 0.f, 0.f};
  #pragma unroll
  for (int kk = 0; kk < 4; ++kk) {
    short8 afm[4];
    #pragma unroll
    for (int m = 0; m < 4; ++m)
      afm[m] = *(const short8*)&et[m * 16 + r16][kk * 32 + quad * 8];
    #pragma unroll
    for (int nt = 0; nt < 4; ++nt)
      #pragma unroll
      for (int m = 0; m < 4; ++m)
        acc[m * 4 + nt] = __builtin_amdgcn_mfma_f32_16x16x32_bf16(afm[m], wb1[kk * 4 + nt], acc[m * 4 + nt], 0, 0, 0);
  }
  #pragma unroll
  for (int nt = 0; nt < 4; ++nt) {
    int n = wave * 64 + nt * 16 + r16;
    float bias = b1f[n];
    #pragma unroll
    for (int m = 0; m < 4; ++m)
      #pragma unroll
      for (int r = 0; r < 4; ++r)
        Hl[m * 16 + quad * 4 + r][n] = f2bfu(fmaxf(acc[m * 4 + nt][r] + bias, 0.f));
  }
  // ---- preload wave's w2 quarter (n in [wave*32, wave*32+32)); latency hides under barrier ----
  short8 wb2[16];
  #pragma unroll
  for (int kk = 0; kk < 8; ++kk)
    #pragma unroll
    for (int nt = 0; nt < 2; ++nt)
      wb2[kk * 2 + nt] = *(const short8*)(wc2 + (size_t)(wave * 32 + nt * 16 + r16) * 256 + kk * 32 + quad * 8);
  __syncthreads();   // Hl columns are cross-wave

  // ---- stage 2: out[64 px][wave's 32 ch] = H*W2^T + b2 + et ----
  f32x4 acc2[8];
  #pragma unroll
  for (int i = 0; i < 8; ++i) acc2[i] = (f32x4){0.f, 0.f, 0.f, 0.f};
  #pragma unroll
  for (int kk = 0; kk < 8; ++kk) {
    short8 afm[4];
    #pragma unroll
    for (int m = 0; m < 4; ++m)
      afm[m] = *(const short8*)&Hl[m * 16 + r16][kk * 32 + quad * 8];
    #pragma unroll
    for (int nt = 0; nt < 2; ++nt)
      #pragma unroll
      for (int m = 0; m < 4; ++m)
        acc2[m * 2 + nt] = __builtin_amdgcn_mfma_f32_16x16x32_bf16(afm[m], wb2[kk * 2 + nt], acc2[m * 2 + nt], 0, 0, 0);
  }
  #pragma unroll
  for (int nt = 0; nt < 2; ++nt) {
    int n = wave * 32 + nt * 16 + r16;
    float bias = b2f[n];
    #pragma unroll
    for (int m = 0; m < 4; ++m) {
      int mloc0 = m * 16 + quad * 4;
      float4 o;
      o.x = acc2[m * 2 + nt][0] + bias + bfu2f(et[mloc0 + 0][n]);
      o.y = acc2[m * 2 + nt][1] + bias + bfu2f(et[mloc0 + 1][n]);
      o.z = acc2[m * 2 + nt][2] + bias + bfu2f(et[mloc0 + 2][n]);
      o.w = acc2[m * 2 + nt][3] + bias + bfu2f(et[mloc0 + 3][n]);
      *(float4*)(outp + (size_t)(b * CD + n) * PD + p0b + mloc0) = o;
    }
  }
}

extern "C" void kernel_launch(void* const* d_in, const int* in_sizes, int n_in,
                              void* d_out, int out_size, void* d_ws, size_t ws_size,
                              hipStream_t stream) {
  // dict order: x, gn_weight(128), gn_bias(128), w1(32768), b1(256), w2(32768), b2(128)
  const void* x  = d_in[0];
  const void* gw = d_in[1];
  const void* gb = d_in[2];
  const void* w1 = d_in[3];
  const void* b1 = d_in[4];
  const void* w2 = d_in[5];
  const void* b2 = d_in[6];
  float* out = (float*)d_out;

  char* ws = (char*)d_ws;
  int* flag = (int*)ws;                                      // [0,16)
  int* cnt = (int*)(ws + 16);                                // [16,128)
  unsigned long long* dmm = (unsigned long long*)(ws + 128); // [128,256)
  float* gn = (float*)(ws + 256);                            // [256,1280)
  float* prm = (float*)(ws + 1280);                          // 2560 B -> 3840
  unsigned short* wc = (unsigned short*)(ws + 3840);         // 131072 -> 134912
  double* avg = (double*)(ws + 134912);                      // 589824 -> 724736
  double* nrm = (double*)(ws + 724736);                      // 589824 -> 1314560
  double* nrm2 = (double*)(ws + 1314560);                    // 589824 -> 1904384
  double* gpart = (double*)(ws + 1904384);                   // 294912 -> 2199296
  unsigned short* eg = (unsigned short*)(ws + 2199296);      // 18874368 -> 21073664
  float* xpm = (float*)(ws + 21073664);                      // 37748736 -> ~58.8 MB

  k_init<<<1, 64, 0, stream>>>(dmm, cnt);
  k_detect<<<64, 256, 0, stream>>>((const unsigned int*)x, cnt);
  k_flag<<<1, 1, 0, stream>>>(cnt, flag);
  k_cvtw<<<256, 256, 0, stream>>>(w1, w2, wc, flag);
  k_cvtb<<<1, 256, 0, stream>>>(gw, gb, b1, b2, prm, flag);
  k_pmt<<<ND / 64, 256, 0, stream>>>(x, flag, xpm, avg, nrm, nrm2, gpart);
  k_gn2<<<128, 64, 0, stream>>>(gpart, gn);
  k_minmax<<<ND / 256, 256, 0, stream>>>(avg, dmm);
  k_ipg<<<ND / 64, 256, 0, stream>>>(xpm, avg, nrm, nrm2, dmm, gn, prm, eg);
  k_ffn<<<ND / 64, 256, 0, stream>>>(eg, prm, wc, out);
}

// Round 8
// 188.251 us; speedup vs baseline: 1.0211x; 1.0211x over previous
//
#include <hip/hip_runtime.h>

#define BD 8
#define CD 128
#define HD 96
#define WD 96
#define PD 9216      // H*W
#define ND 73728     // B*P

typedef __attribute__((ext_vector_type(8))) short short8;
typedef __attribute__((ext_vector_type(4))) float f32x4;

__device__ inline float bfu2f(unsigned int u) { return __uint_as_float(u << 16); }
__device__ inline unsigned short f2bfu(float f) {
  unsigned int u = __float_as_uint(f);
  u += 0x7fffu + ((u >> 16) & 1u);   // RNE
  return (unsigned short)(u >> 16);
}

template<bool F32>
__device__ __forceinline__ float ldv(const void* __restrict__ p, size_t i) {
  if constexpr (F32) return ((const float*)p)[i];
  else return bfu2f(((const unsigned short*)p)[i]);
}

// ---------------- init: dmm min/max slots + detect counters ----------------
__global__ void k_init(unsigned long long* dmm, int* cnt) {
  int t = threadIdx.x;
  if (t < 8) dmm[t] = 0x7FEFFFFFFFFFFFFFULL;  // min slots (DBL_MAX bits)
  else if (t < 16) dmm[t] = 0ULL;             // max slots
  if (t == 16) { cnt[0] = 0; cnt[1] = 0; }
}

// ---------------- storage-dtype detector ----------------
__global__ void k_detect(const unsigned int* __restrict__ xw, int* __restrict__ cnt) {
  int t = blockIdx.x * 256 + threadIdx.x;     // 64 blocks -> 16384 uint4 = 65536 words
  uint4 w = ((const uint4*)xw)[t];
  int lz = (int)((w.x & 0xFFFFu) == 0u) + (int)((w.y & 0xFFFFu) == 0u) +
           (int)((w.z & 0xFFFFu) == 0u) + (int)((w.w & 0xFFFFu) == 0u);
  int e2 = (int)(((w.x >> 7) & 0xFFu) == 0xFFu) + (int)(((w.y >> 7) & 0xFFu) == 0xFFu) +
           (int)(((w.z >> 7) & 0xFFu) == 0xFFu) + (int)(((w.w >> 7) & 0xFFu) == 0xFFu);
  #pragma unroll
  for (int off = 32; off; off >>= 1) {
    lz += __shfl_down(lz, off);
    e2 += __shfl_down(e2, off);
  }
  if ((threadIdx.x & 63) == 0) { atomicAdd(&cnt[0], lz); atomicAdd(&cnt[1], e2); }
}

__global__ void k_flag(const int* __restrict__ cnt, int* __restrict__ flag) {
  *flag = (cnt[0] > 4096 || cnt[1] > 0) ? 1 : 0;  // 1 = float32 storage
}

// ---------------- canonical bf16 weights for MFMA B-operands ----------------
__global__ void k_cvtw(const void* __restrict__ w1, const void* __restrict__ w2,
                       unsigned short* __restrict__ wc, const int* __restrict__ flag) {
  bool f32 = (*flag != 0);
  int t = blockIdx.x * 256 + threadIdx.x;   // 0..65535
  if (t < 32768)
    wc[t] = f32 ? f2bfu(((const float*)w1)[t]) : ((const unsigned short*)w1)[t];
  else {
    int u = t - 32768;
    wc[t] = f32 ? f2bfu(((const float*)w2)[u]) : ((const unsigned short*)w2)[u];
  }
}

// ---------------- canonical f32 small params: gw(128) gb(128) b1(256) b2(128) ----------------
__global__ void k_cvtb(const void* __restrict__ gw, const void* __restrict__ gb,
                       const void* __restrict__ b1, const void* __restrict__ b2,
                       float* __restrict__ prm, const int* __restrict__ flag) {
  bool f32 = (*flag != 0);
  int t = threadIdx.x;
  for (int i = t; i < 640; i += 256) {
    float v;
    if (i < 128)      v = f32 ? ((const float*)gw)[i]       : bfu2f(((const unsigned short*)gw)[i]);
    else if (i < 256) v = f32 ? ((const float*)gb)[i - 128] : bfu2f(((const unsigned short*)gb)[i - 128]);
    else if (i < 512) v = f32 ? ((const float*)b1)[i - 256] : bfu2f(((const unsigned short*)b1)[i - 256]);
    else              v = f32 ? ((const float*)b2)[i - 512] : bfu2f(((const unsigned short*)b2)[i - 512]);
    prm[i] = v;
  }
}

// ---------------- transpose -> pixel-major f32 xpm + channel stats + GN partials ----------------
// XCD-swizzled (same image->XCD pinning as k_ipg). nrm2 = quarter-associated
// sum(v^2): EXACTLY the chain k_ipg's center dot would produce -> k_ipg skips
// the k=4 dot bit-identically. nrm keeps the original sequential chain.
template<bool F32>
__device__ __forceinline__ void pmt_body(const void* __restrict__ x,
                                         float* __restrict__ xpm,
                                         double* __restrict__ avg, double* __restrict__ nrm,
                                         double* __restrict__ nrm2,
                                         double* __restrict__ gpart,
                                         float (*tile)[132], int lb) {
  const int t = threadIdx.x, px = t & 63, ci = t >> 6;
  const int gp0 = lb * 64, b = gp0 / PD, p0 = gp0 - b * PD;
  double sg[4] = {0.0, 0.0, 0.0, 0.0}, qg[4] = {0.0, 0.0, 0.0, 0.0};
  for (int j = 0; j < 32; ++j) {
    int c = ci * 32 + j;
    float v = ldv<F32>(x, (size_t)(b * CD + c) * PD + p0 + px);   // coalesced
    tile[px][c] = v;
    sg[j >> 3] += (double)v;
    qg[j >> 3] += (double)v * (double)v;
  }
  #pragma unroll
  for (int g = 0; g < 4; ++g) {
    #pragma unroll
    for (int off = 32; off; off >>= 1) {
      sg[g] += __shfl_down(sg[g], off);
      qg[g] += __shfl_down(qg[g], off);
    }
  }
  if (px == 0) {
    double* gp_ = gpart + (size_t)lb * 32;
    #pragma unroll
    for (int g = 0; g < 4; ++g) {
      gp_[(ci * 4 + g) * 2 + 0] = sg[g];
      gp_[(ci * 4 + g) * 2 + 1] = qg[g];
    }
  }
  __syncthreads();
  for (int i = t; i < 2048; i += 256) {
    int r = i >> 5, seg = i & 31;
    *(float4*)(xpm + (size_t)(gp0 + r) * 128 + seg * 4) = *(const float4*)&tile[r][seg * 4];
  }
  if (t < 64) {
    double s = 0.0, q = 0.0;
    for (int c = 0; c < 128; ++c) {
      float v = tile[t][c];
      s += (double)v;
      q += (double)v * (double)v;
    }
    double qq[4] = {0.0, 0.0, 0.0, 0.0};
    #pragma unroll
    for (int g = 0; g < 4; ++g)
      for (int i = 0; i < 32; ++i) {
        float v = tile[t][g * 32 + i];
        qq[g] += (double)v * (double)v;
      }
    avg[gp0 + t] = s * (1.0 / 128.0);
    nrm[gp0 + t] = sqrt(q);
    nrm2[gp0 + t] = ((qq[0] + qq[1]) + qq[2]) + qq[3];
  }
}
__global__ __launch_bounds__(256) void k_pmt(const void* __restrict__ x,
                                             const int* __restrict__ flag,
                                             float* __restrict__ xpm,
                                             double* __restrict__ avg,
                                             double* __restrict__ nrm,
                                             double* __restrict__ nrm2,
                                             double* __restrict__ gpart) {
  __shared__ float tile[64][132];
  const int lb = (blockIdx.x & 7) * 144 + (blockIdx.x >> 3);  // XCD swizzle (1152 = 8*144)
  if (*flag) pmt_body<true>(x, xpm, avg, nrm, nrm2, gpart, tile, lb);
  else pmt_body<false>(x, xpm, avg, nrm, nrm2, gpart, tile, lb);
}

// ---------------- GN finalize: fold 144 block-partials per (b,g) ----------------
__global__ void k_gn2(const double* __restrict__ gpart, float* __restrict__ gn) {
  const int bg = blockIdx.x;                 // b*16 + g
  const int b = bg >> 4, g = bg & 15;
  const int t = threadIdx.x;                 // 64 threads
  double s = 0.0, q = 0.0;
  for (int i = t; i < 144; i += 64) {
    const double* pp = gpart + (size_t)(b * 144 + i) * 32 + g * 2;
    s += pp[0];
    q += pp[1];
  }
  #pragma unroll
  for (int off = 32; off; off >>= 1) {
    s += __shfl_down(s, off);
    q += __shfl_down(q, off);
  }
  if (t == 0) {
    double mu = s / 73728.0;
    double var = q / 73728.0 - mu * mu;
    gn[bg] = (float)mu;
    gn[128 + bg] = (float)(1.0 / sqrt(var + 1e-5));
  }
}

// zero-padded Laplacian on the mean map
__device__ inline double lap_df(const double* __restrict__ a, int b, int y, int x) {
  const double* ab = a + (size_t)b * PD;
  double v = 4.0 * ab[y * WD + x];
  if (y > 0)      v -= ab[(y - 1) * WD + x];
  if (y < HD - 1) v -= ab[(y + 1) * WD + x];
  if (x > 0)      v -= ab[y * WD + x - 1];
  if (x < WD - 1) v -= ab[y * WD + x + 1];
  return fabs(v);
}

// ---------------- per-batch min/max of df; persists df per pixel (dfb) ----------------
__global__ void k_minmax(const double* __restrict__ avg, unsigned long long* __restrict__ dmm,
                         double* __restrict__ dfb) {
  __shared__ double mnW[4], mxW[4];
  int t = threadIdx.x;
  const int lb = (blockIdx.x & 7) * 36 + (blockIdx.x >> 3);   // XCD swizzle (288 = 8*36)
  int gp = lb * 256 + t;                    // 256 | PD -> block never crosses batch
  int b = gp / PD, p = gp - b * PD;
  double df = lap_df(avg, b, p / WD, p % WD);
  dfb[gp] = df;                             // k_ipg phase 1b reads this (1 load vs 5)
  double mn = df, mx = df;
  #pragma unroll
  for (int off = 32; off; off >>= 1) {
    mn = fmin(mn, __shfl_down(mn, off));
    mx = fmax(mx, __shfl_down(mx, off));
  }
  if ((t & 63) == 0) { mnW[t >> 6] = mn; mxW[t >> 6] = mx; }
  __syncthreads();
  if (t == 0) {
    mn = fmin(fmin(mnW[0], mnW[1]), fmin(mnW[2], mnW[3]));
    mx = fmax(fmax(mxW[0], mxW[1]), fmax(mxW[2], mxW[3]));
    atomicMin(&dmm[b], (unsigned long long)__double_as_longlong(mn));
    atomicMax(&dmm[b + 8], (unsigned long long)__double_as_longlong(mx));
  }
}

// ---------------- k_ipg: IPG + GN -> eg, 8x8 tiles + LDS halo ----------------
// r8: reverted r7's divergent symmetric-dot scheme (waves executed all fallback
// branches anyway -> pure overhead). Kept the UNIFORM savings: k=4 center dot
// == nrm2 (chain-identical, from k_pmt). NEW: phase 1b is LDS-fed - nrm halo
// (reflect applied at staging -> values identical to neigh9 lookups) and nrm2
// staged to LDS; df read from dfb (computed by k_minmax). The 16-active-lane
// phase no longer chains ~15 global loads.
__global__ __launch_bounds__(256, 3) void k_ipg(const float* __restrict__ xpm,
                                                const double* __restrict__ nrm,
                                                const double* __restrict__ nrm2,
                                                const double* __restrict__ dfb,
                                                const unsigned long long* __restrict__ dmm,
                                                const float* __restrict__ gn,
                                                const float* __restrict__ prm,
                                                unsigned short* __restrict__ eg) {
  __shared__ float tileF[12800];            // 51200 B halo: 10x10 px x 128 ch f32
  __shared__ double nsl[100];               // 800 B: nrm for the 10x10 halo (reflected)
  __shared__ double nsl2[64];               // 512 B: nrm2 (center dots) for tile pixels
  float4* tile4 = (float4*)tileF;
  const float* gwf = prm;
  const float* gbf = prm + 128;

  const int t = threadIdx.x;
  const int lb = (blockIdx.x & 7) * 144 + (blockIdx.x >> 3);  // XCD swizzle (1152 = 8*144)
  const int b = lb / 144;
  const int tid = lb - b * 144;
  const int ty = tid / 12, tx = tid - ty * 12;                // 12x12 tiles of 8x8
  const int y0 = ty * 8, x0 = tx * 8;

  // ---- stage halo (XOR-swizzled) + nrm halo + nrm2 tile ----
  {
    const int s = t & 31, hpb = t >> 5;
    #pragma unroll
    for (int it = 0; it < 13; ++it) {
      int hp = it * 8 + hpb;
      if (hp < 100) {
        int hr = hp / 10, hc = hp - hr * 10;
        int gy = y0 - 1 + hr; gy = gy < 0 ? -gy : (gy >= HD ? 2 * HD - 2 - gy : gy);
        int gx = x0 - 1 + hc; gx = gx < 0 ? -gx : (gx >= WD ? 2 * WD - 2 - gx : gx);
        const float4* src = (const float4*)(xpm + (size_t)(b * PD + gy * WD + gx) * 128) + s;
        tile4[(hp * 32 + s) ^ (hp & 7)] = *src;
      }
    }
    if (t < 100) {
      int hr = t / 10, hc = t - hr * 10;
      int gy = y0 - 1 + hr; gy = gy < 0 ? -gy : (gy >= HD ? 2 * HD - 2 - gy : gy);
      int gx = x0 - 1 + hc; gx = gx < 0 ? -gx : (gx >= WD ? 2 * WD - 2 - gx : gx);
      nsl[t] = nrm[b * PD + gy * WD + gx];    // reflected -> identical to neigh9 lookups
    } else if (t >= 128 && t < 192) {
      int a2 = t - 128;
      nsl2[a2] = nrm2[b * PD + (y0 + (a2 >> 3)) * WD + x0 + (a2 & 7)];
    }
  }
  __syncthreads();

  const int a = t >> 2, q = t & 3;            // pixel-in-tile, channel quarter
  const int yl = a >> 3, xl = a & 7;
  const int y = y0 + yl, xx = x0 + xl;
  const int p = y * WD + xx;
  const int cpix = (yl + 1) * 10 + (xl + 1);
  const int cub = cpix * 32 + q * 8, csw = cpix & 7;

  // ---- phase 1a: f64 dots k!=4 (uniform), cross-quarter reduced ----
  double sd[9];
  {
    float cv[32];
    #pragma unroll
    for (int j4 = 0; j4 < 8; ++j4)
      *(float4*)(cv + 4 * j4) = tile4[(cub + j4) ^ csw];
    #pragma unroll
    for (int k = 0; k < 9; ++k) {
      if (k == 4) continue;                   // center == nrm2 (chain-identical)
      int dy = k / 3, dx = k - dy * 3;
      int pix = (yl + dy) * 10 + (xl + dx);
      int ub = pix * 32 + q * 8, sw = pix & 7;
      double acc = 0.0;
      #pragma unroll
      for (int seg = 0; seg < 8; ++seg) {
        float4 nv = tile4[(ub + seg) ^ sw];
        acc += (double)cv[seg * 4 + 0] * (double)nv.x;
        acc += (double)cv[seg * 4 + 1] * (double)nv.y;
        acc += (double)cv[seg * 4 + 2] * (double)nv.z;
        acc += (double)cv[seg * 4 + 3] * (double)nv.w;
      }
      // cross-quarter sum in-wave, SAME association as original: ((q0+q1)+q2)+q3
      double v1 = __shfl_down(acc, 1);
      double v2 = __shfl_down(acc, 2);
      double v3 = __shfl_down(acc, 3);
      sd[k] = ((acc + v1) + v2) + v3;
    }
  }

  // ---- phase 1b: count, ranks, softmax weights (q==0 lanes; LDS-fed) ----
  float wv[9];
  #pragma unroll
  for (int j = 0; j < 9; ++j) wv[j] = 0.f;
  if (q == 0) {
    double dmin = __longlong_as_double((long long)dmm[b]);
    double dmax = __longlong_as_double((long long)dmm[b + 8]);
    double df = dfb[b * PD + p];
    double dn = (df - dmin) / (dmax - dmin + 1e-8);
    int kk = 1 + (int)rint(dn * 7.0);
    kk = kk < 1 ? 1 : (kk > 8 ? 8 : kk);

    sd[4] = nsl2[a];
    double np_ = fmax(nsl[cpix], 1e-12);
    #pragma unroll
    for (int k = 0; k < 9; ++k) {
      int dy = k / 3, dx = k - dy * 3;
      double nq = fmax(nsl[(yl + dy) * 10 + (xl + dx)], 1e-12);
      sd[k] = sd[k] / (np_ * nq);           // normalized sim
    }
    float w[9];
    float wsum = 0.f;
    #pragma unroll
    for (int j = 0; j < 9; ++j) {
      int rank = 0;
      #pragma unroll
      for (int i = 0; i < 9; ++i)
        rank += (sd[i] > sd[j]) || (sd[i] == sd[j] && i < j);   // stable tie rule
      w[j] = (rank < kk) ? expf((float)sd[j]) : 0.f;
      wsum += w[j];
    }
    float inv = 1.f / wsum;
    #pragma unroll
    for (int j = 0; j < 9; ++j) wv[j] = w[j] * inv;
  }
  #pragma unroll
  for (int j = 0; j < 9; ++j) wv[j] = __shfl(wv[j], (t & 63) & ~3);  // broadcast to quarters

  // ---- phase 1c: aggregate (LDS) + GroupNorm -> eg (bf16, pixel-major) ----
  {
    float og[32];
    #pragma unroll
    for (int j = 0; j < 32; ++j) og[j] = 0.f;
    #pragma unroll
    for (int k = 0; k < 9; ++k) {
      int dy = k / 3, dx = k - dy * 3;
      int pix = (yl + dy) * 10 + (xl + dx);
      int ub = pix * 32 + q * 8, sw = pix & 7;
      #pragma unroll
      for (int seg = 0; seg < 8; ++seg) {
        float4 nv = tile4[(ub + seg) ^ sw];
        og[seg * 4 + 0] += wv[k] * nv.x;
        og[seg * 4 + 1] += wv[k] * nv.y;
        og[seg * 4 + 2] += wv[k] * nv.z;
        og[seg * 4 + 3] += wv[k] * nv.w;
      }
    }
    const int g16 = b * 16;
    unsigned short* egr = eg + (size_t)(b * PD + p) * 128 + q * 32;
    #pragma unroll
    for (int seg = 0; seg < 4; ++seg) {
      float4 cA = tile4[(cub + seg * 2) ^ csw];       // center re-read (bit-identical)
      float4 cB = tile4[(cub + seg * 2 + 1) ^ csw];
      float cvv[8] = {cA.x, cA.y, cA.z, cA.w, cB.x, cB.y, cB.z, cB.w};
      int g = q * 4 + seg;
      float mu = gn[g16 + g], rs = gn[128 + g16 + g];
      unsigned int pkd[4];
      #pragma unroll
      for (int j = 0; j < 8; ++j) {
        int c = q * 32 + seg * 8 + j;
        float e = og[seg * 8 + j] + (cvv[j] - mu) * rs * gwf[c] + gbf[c];
        unsigned int h = (unsigned int)f2bfu(e);
        if (j & 1) pkd[j >> 1] |= h << 16;
        else pkd[j >> 1] = h;
      }
      uint4 v; v.x = pkd[0]; v.y = pkd[1]; v.z = pkd[2]; v.w = pkd[3];
      *(uint4*)(egr + seg * 8) = v;                   // 16B store; wave covers 4KB contiguous
    }
  }
}

// ---------------- k_ffn: eg -> FFN -> out, wave-per-N-quarter (weights in regs) ----------------
__global__ __launch_bounds__(256, 3) void k_ffn(const unsigned short* __restrict__ eg,
                                                const float* __restrict__ prm,
                                                const unsigned short* __restrict__ wc,
                                                float* __restrict__ outp) {
  __shared__ unsigned short et[64][136];    // 17408 B
  __shared__ unsigned short Hl[64][264];    // 33792 B
  const float* b1f = prm + 256;
  const float* b2f = prm + 512;

  const int t = threadIdx.x;
  const int lb = (blockIdx.x & 7) * 144 + (blockIdx.x >> 3);  // XCD swizzle: match k_ipg
  const int gp0 = lb * 64;                  // 64 | PD -> block within one batch
  const int b = gp0 / PD, p0b = gp0 - b * PD;

  const unsigned short* wc1 = wc;          // w1 [256][128]
  const unsigned short* wc2 = wc + 32768;  // w2 [128][256]
  const int lane = t & 63, wave = t >> 6;
  const int r16 = lane & 15, quad = lane >> 4;

  // ---- stage eg rows -> et LDS (16 KB contiguous, fully coalesced) ----
  {
    const uint4* eg4 = (const uint4*)(eg + (size_t)gp0 * 128);
    #pragma unroll
    for (int it = 0; it < 4; ++it) {
      int lin = it * 256 + t;               // 1024 uint4 = 64 rows x 16
      int row = lin >> 4, c8 = lin & 15;
      *(uint4*)&et[row][c8 * 8] = eg4[lin];
    }
  }
  // ---- preload wave's w1 quarter (n in [wave*64, wave*64+64)) into regs ----
  short8 wb1[16];
  #pragma unroll
  for (int kk = 0; kk < 4; ++kk)
    #pragma unroll
    for (int nt = 0; nt < 4; ++nt)
      wb1[kk * 4 + nt] = *(const short8*)(wc1 + (size_t)(wave * 64 + nt * 16 + r16) * 128 + kk * 32 + quad * 8);
  __syncthreads();

  // ---- stage 1: H[64 px][wave's 64 n] = relu(et * W1^T + b1), pure-reg MFMA ----
  f32x4 acc[16];
  #pragma unroll
  for (int i = 0; i < 16; ++i) acc[i] = (f32x4){0.f, 0.f, 0.f, 0.f};
  #pragma unroll
  for (int kk = 0; kk < 4; ++kk) {
    short8 afm[4];
    #pragma unroll
    for (int m = 0; m < 4; ++m)
      afm[m] = *(const short8*)&et[m * 16 + r16][kk * 32 + quad * 8];
    #pragma unroll
    for (int nt = 0; nt < 4; ++nt)
      #pragma unroll
      for (int m = 0; m < 4; ++m)
        acc[m * 4 + nt] = __builtin_amdgcn_mfma_f32_16x16x32_bf16(afm[m], wb1[kk * 4 + nt], acc[m * 4 + nt], 0, 0, 0);
  }
  #pragma unroll
  for (int nt = 0; nt < 4; ++nt) {
    int n = wave * 64 + nt * 16 + r16;
    float bias = b1f[n];
    #pragma unroll
    for (int m = 0; m < 4; ++m)
      #pragma unroll
      for (int r = 0; r < 4; ++r)
        Hl[m * 16 + quad * 4 + r][n] = f2bfu(fmaxf(acc[m * 4 + nt][r] + bias, 0.f));
  }
  // ---- preload wave's w2 quarter; latency hides under barrier ----
  short8 wb2[16];
  #pragma unroll
  for (int kk = 0; kk < 8; ++kk)
    #pragma unroll
    for (int nt = 0; nt < 2; ++nt)
      wb2[kk * 2 + nt] = *(const short8*)(wc2 + (size_t)(wave * 32 + nt * 16 + r16) * 256 + kk * 32 + quad * 8);
  __syncthreads();   // Hl columns are cross-wave

  // ---- stage 2: out[64 px][wave's 32 ch] = H*W2^T + b2 + et ----
  f32x4 acc2[8];
  #pragma unroll
  for (int i = 0; i < 8; ++i) acc2[i] = (f32x4){0.f, 0.f, 0.f, 0.f};
  #pragma unroll
  for (int kk = 0; kk < 8; ++kk) {
    short8 afm[4];
    #pragma unroll
    for (int m = 0; m < 4; ++m)
      afm[m] = *(const short8*)&Hl[m * 16 + r16][kk * 32 + quad * 8];
    #pragma unroll
    for (int nt = 0; nt < 2; ++nt)
      #pragma unroll
      for (int m = 0; m < 4; ++m)
        acc2[m * 2 + nt] = __builtin_amdgcn_mfma_f32_16x16x32_bf16(afm[m], wb2[kk * 2 + nt], acc2[m * 2 + nt], 0, 0, 0);
  }
  #pragma unroll
  for (int nt = 0; nt < 2; ++nt) {
    int n = wave * 32 + nt * 16 + r16;
    float bias = b2f[n];
    #pragma unroll
    for (int m = 0; m < 4; ++m) {
      int mloc0 = m * 16 + quad * 4;
      float4 o;
      o.x = acc2[m * 2 + nt][0] + bias + bfu2f(et[mloc0 + 0][n]);
      o.y = acc2[m * 2 + nt][1] + bias + bfu2f(et[mloc0 + 1][n]);
      o.z = acc2[m * 2 + nt][2] + bias + bfu2f(et[mloc0 + 2][n]);
      o.w = acc2[m * 2 + nt][3] + bias + bfu2f(et[mloc0 + 3][n]);
      *(float4*)(outp + (size_t)(b * CD + n) * PD + p0b + mloc0) = o;
    }
  }
}

extern "C" void kernel_launch(void* const* d_in, const int* in_sizes, int n_in,
                              void* d_out, int out_size, void* d_ws, size_t ws_size,
                              hipStream_t stream) {
  // dict order: x, gn_weight(128), gn_bias(128), w1(32768), b1(256), w2(32768), b2(128)
  const void* x  = d_in[0];
  const void* gw = d_in[1];
  const void* gb = d_in[2];
  const void* w1 = d_in[3];
  const void* b1 = d_in[4];
  const void* w2 = d_in[5];
  const void* b2 = d_in[6];
  float* out = (float*)d_out;

  char* ws = (char*)d_ws;
  int* flag = (int*)ws;                                      // [0,16)
  int* cnt = (int*)(ws + 16);                                // [16,128)
  unsigned long long* dmm = (unsigned long long*)(ws + 128); // [128,256)
  float* gn = (float*)(ws + 256);                            // [256,1280)
  float* prm = (float*)(ws + 1280);                          // 2560 B -> 3840
  unsigned short* wc = (unsigned short*)(ws + 3840);         // 131072 -> 134912
  double* avg = (double*)(ws + 134912);                      // 589824 -> 724736
  double* nrm = (double*)(ws + 724736);                      // 589824 -> 1314560
  double* nrm2 = (double*)(ws + 1314560);                    // 589824 -> 1904384
  double* gpart = (double*)(ws + 1904384);                   // 294912 -> 2199296
  double* dfb = (double*)(ws + 2199296);                     // 589824 -> 2789120
  unsigned short* eg = (unsigned short*)(ws + 2789120);      // 18874368 -> 21663488
  float* xpm = (float*)(ws + 21663488);                      // 37748736 -> ~59.4 MB

  k_init<<<1, 64, 0, stream>>>(dmm, cnt);
  k_detect<<<64, 256, 0, stream>>>((const unsigned int*)x, cnt);
  k_flag<<<1, 1, 0, stream>>>(cnt, flag);
  k_cvtw<<<256, 256, 0, stream>>>(w1, w2, wc, flag);
  k_cvtb<<<1, 256, 0, stream>>>(gw, gb, b1, b2, prm, flag);
  k_pmt<<<ND / 64, 256, 0, stream>>>(x, flag, xpm, avg, nrm, nrm2, gpart);
  k_gn2<<<128, 64, 0, stream>>>(gpart, gn);
  k_minmax<<<ND / 256, 256, 0, stream>>>(avg, dmm, dfb);
  k_ipg<<<ND / 64, 256, 0, stream>>>(xpm, nrm, nrm2, dfb, dmm, gn, prm, eg);
  k_ffn<<<ND / 64, 256, 0, stream>>>(eg, prm, wc, out);
}